// Round 1
// baseline (71.836 us; speedup 1.0000x reference)
//
#include <hip/hip_runtime.h>

#define N_CAMP 50
#define DAYS   365
#define BASIS  1e-10f
#define BATCH  4096

// One block per batch element b. Thread t handles day d = t (t < 365).
// Reads adstock[b, c, d+1] for c = 0..49 -- consecutive lanes hit consecutive
// addresses (coalesced). Betas staged in LDS, broadcast-read.
__global__ __launch_bounds__(384)
void transition_prob_kernel(const float* __restrict__ adstock,
                            const float* __restrict__ mu,
                            const float* __restrict__ beta,
                            float* __restrict__ out)
{
    __shared__ float sb0[N_CAMP];
    __shared__ float sb1[N_CAMP];
    __shared__ float sb2[N_CAMP];
    __shared__ float smu[3];

    const int tid = threadIdx.x;
    const int b   = blockIdx.x;

    // Stage beta (150 floats) and mu (3 floats) in LDS.
    if (tid < 3 * N_CAMP) {
        const int c = tid / 3;
        const int k = tid % 3;
        const float v = beta[tid];
        if (k == 0) sb0[c] = v;
        else if (k == 1) sb1[c] = v;
        else sb2[c] = v;
    }
    if (tid < 3) smu[tid] = mu[tid];
    __syncthreads();

    const int d = tid;
    if (d < DAYS) {
        const float* arow = adstock + (size_t)b * (N_CAMP * (DAYS + 1)) + (d + 1);

        float o1 = 0.f, o2 = 0.f, o3 = 0.f;
#pragma unroll
        for (int c = 0; c < N_CAMP; ++c) {
            const float a = arow[(size_t)c * (DAYS + 1)];
            o1 = fmaf(a, sb0[c], o1);
            o2 = fmaf(a, sb1[c], o2);
            o3 = fmaf(a, sb2[c], o3);
        }

        const float e1 = expf(smu[0] + o1);
        const float e2 = expf(smu[1] + o2);
        const float e3 = expf(smu[2] + o3);
        const float inv0 = 1.0f / (1.0f + e1);
        const float inv1 = 1.0f / (1.0f + e2 + e3);

        float* q = out + ((size_t)b * DAYS + d) * 9;
        q[0] = fmaxf(inv0,      BASIS);  // Q00 = 1/den0
        q[1] = fmaxf(e1 * inv0, BASIS);  // Q01 = num[0,1]/den0
        q[2] = BASIS;                    // Q02 = max(0, B)
        q[3] = fmaxf(e2 * inv1, BASIS);  // Q10 = num[1,0]/den1
        q[4] = fmaxf(inv1,      BASIS);  // Q11 = 1/den1
        q[5] = fmaxf(e3 * inv1, BASIS);  // Q12 = num[1,1]/den1
        q[6] = BASIS;                    // Q20
        q[7] = BASIS;                    // Q21
        q[8] = 1.0f;                     // Q22 = max(1, B)
    }
}

__global__ void scalar_tail_kernel(const float* __restrict__ init_prob,
                                   const float* __restrict__ click_prob,
                                   float* __restrict__ out)
{
    // sigmoid of the two scalars, appended after Q.
    const size_t base = (size_t)BATCH * DAYS * 9;
    if (threadIdx.x == 0) {
        out[base + 0] = 1.0f / (1.0f + expf(-init_prob[0]));
        out[base + 1] = 1.0f / (1.0f + expf(-click_prob[0]));
    }
}

extern "C" void kernel_launch(void* const* d_in, const int* in_sizes, int n_in,
                              void* d_out, int out_size, void* d_ws, size_t ws_size,
                              hipStream_t stream)
{
    const float* adstock    = (const float*)d_in[0];
    const float* mu         = (const float*)d_in[1];
    const float* beta       = (const float*)d_in[2];
    const float* init_prob  = (const float*)d_in[3];
    const float* click_prob = (const float*)d_in[4];
    float* out = (float*)d_out;

    dim3 grid(BATCH);
    dim3 block(384);
    transition_prob_kernel<<<grid, block, 0, stream>>>(adstock, mu, beta, out);
    scalar_tail_kernel<<<1, 64, 0, stream>>>(init_prob, click_prob, out);
}